// Round 3
// baseline (433.777 us; speedup 1.0000x reference)
//
#include <hip/hip_runtime.h>
#include <stdint.h>

#define B_ 8
#define T_ 512
#define M_ 16
#define D_ 128
#define P_ 256
#define H_ 8
#define E_ 32

typedef __attribute__((ext_vector_type(8))) short  short8;
typedef __attribute__((ext_vector_type(4))) short  short4v;
typedef __attribute__((ext_vector_type(4))) float  float4v;
typedef __attribute__((ext_vector_type(2))) unsigned int uint2v;
typedef __attribute__((ext_vector_type(4))) unsigned int uint4v;
typedef __attribute__((ext_vector_type(2))) __bf16 bf16x2;

#define MFMA32(a,b,c) __builtin_amdgcn_mfma_f32_16x16x32_bf16(a,b,c,0,0,0)   // K=32, short8 ops
#define EXP2F(x) __builtin_amdgcn_exp2f(x)

#define C2 0.2550332772062413f   // log2(e)/sqrt(E)

// cold-path scalar RNE (prep only)
static __device__ __forceinline__ unsigned short f2bf(float x){
  unsigned int u = __builtin_bit_cast(unsigned int, x);
  u += 0x7FFFu + ((u >> 16) & 1u);           // RNE
  return (unsigned short)(u >> 16);
}

// hot-path: plain __bf16 casts -> compiler emits v_cvt_pk_bf16_f32 (RNE).
static __device__ __forceinline__ unsigned int pk2(float a, float b){
  bf16x2 h; h[0] = (__bf16)a; h[1] = (__bf16)b;
  return __builtin_bit_cast(unsigned int, h);
}

static __device__ __forceinline__ short4v pack4(float4v v){
  uint2v u; u.x = pk2(v[0], v[1]); u.y = pk2(v[2], v[3]);
  return __builtin_bit_cast(short4v, u);
}

static __device__ __forceinline__ short8 pack8(float4v a, float4v b){
  uint4v u; u.x = pk2(a[0],a[1]); u.y = pk2(a[2],a[3]);
  u.z = pk2(b[0],b[1]); u.w = pk2(b[2],b[3]);
  return __builtin_bit_cast(short8, u);
}

static __device__ __forceinline__ short8 cat44(short4v lo, short4v hi){
  short8 r;
  r[0]=lo[0]; r[1]=lo[1]; r[2]=lo[2]; r[3]=lo[3];
  r[4]=hi[0]; r[5]=hi[1]; r[6]=hi[2]; r[7]=hi[3];
  return r;
}

// ------- kernel 0: WT[z][p][d] bf16 (Wq pre-scaled by C2) + maskf transpose -------
// Q and K weight rows are PERMUTED so each projection pass directly produces the
// e-chunk-of-8 lane layout required by the K=32 MFMA operands:
//   storage row w = eh*16 + q4*4 + r  holds true column  e = q4*8 + eh*4 + r.
__global__ void prep(const float* __restrict__ Wq, const float* __restrict__ Wk,
                     const float* __restrict__ Wv, const int* __restrict__ mask,
                     uint16_t* __restrict__ WT, float* __restrict__ maskf){
  int idx = blockIdx.x*256 + threadIdx.x;      // 640*256 = 163840
  if (idx < 3*P_*D_){                          // 98304: weight transpose+cast
    int d = idx & (D_-1);
    int p = (idx >> 7) & (P_-1);
    int z = idx >> 15;
    int col = p;
    if (z < 2){                                // Q, K: permute within-head rows
      int w = p & 31;
      int e = ((w>>2)&3)*8 + ((w>>4)&1)*4 + (w&3);
      col = (p & ~31) | e;
    }
    const float* W = (z==0) ? Wq : (z==1) ? Wk : Wv;
    float sc = (z==0) ? C2 : 1.0f;
    WT[idx] = f2bf(W[d*P_ + col] * sc);
  } else {                                     // 65536: mask -> maskf[(b*M+m)*T+s]
    int j = idx - 3*P_*D_;
    int s = j & (T_-1);
    int bm = j >> 9;
    int b = bm >> 4, m = bm & (M_-1);
    maskf[j] = mask[(b*T_ + s)*M_ + m] ? 0.0f : -1e30f;
  }
}

// ---------------- fused QKV + masked attention, one block per (b,m,h) ------
// OCCUPANCY RESTRUCTURE (r3): rounds 1-2 cut MFMA+VALU work with ZERO wall
// change -> latency-bound at 16 waves/CU (LDS 64KB AND ~128 total regs/wave
// both cap at 2x8 waves). Fix: 1024-thread blocks, 16 waves x 32 t-rows
// (accums halve to 24 regs), __launch_bounds__(1024,8) forces <=64 total
// regs -> 2 blocks x 16 waves = 32 waves/CU. Mask row staged in LDS
// (broadcast b128 reads) removes 32 global loads from the s-loop.
// All MFMAs are K=32 16x16x32 (round-1/2 operand-layout tricks).
__global__ __launch_bounds__(1024, 8) void attn_fused(
    const float* __restrict__ inp, const uint16_t* __restrict__ WT,
    const float* __restrict__ bq, const float* __restrict__ bk,
    const float* __restrict__ bv, const float* __restrict__ maskf,
    float* __restrict__ out){
  __shared__ __align__(16) uint16_t Kb[T_*E_];   // 32768 B  K[s][e] linear-e, slot-swizzled
  __shared__ __align__(16) uint16_t Vt[E_*T_];   // 32768 B  V^T[e][s], u-swizzled
  __shared__ __align__(16) float    Mrow[T_];    //  2048 B  additive mask row

  const int bx = blockIdx.x;                // 1024
  const int h = bx >> 7, bm = bx & 127;     // same-bm blocks -> same XCD (bx%8 = bm%8)
  const int b = bm >> 4, m = bm & 15;
  const int tid = threadIdx.x;
  const int wave = tid >> 6, lane = tid & 63;
  const int q4 = lane >> 4, c = lane & 15;
  const int t0 = wave*32;                   // 16 waves x 32 rows = T

  // stage mask row (f32, coalesced); consumed after the main barrier
  if (tid < T_) Mrow[tid] = maskf[(size_t)bm*T_ + tid];

  // ---- pack inp rows once: rows t0+tj*16+c, full d ----
  short8 af[2][4];   // [tj][kc]
  for (int tj=0; tj<2; tj++){
    const float* src = inp + (size_t)((b*T_ + t0 + tj*16 + c)*M_ + m)*D_;
    for (int kc=0; kc<4; kc++){
      float4v x0 = *(const float4v*)(src + kc*32 + q4*8);
      float4v x1 = *(const float4v*)(src + kc*32 + q4*8 + 4);
      af[tj][kc] = pack8(x0, x1);
    }
  }

  const uint16_t* WQ = WT                       + (size_t)(h*E_)*D_;
  const uint16_t* WK = WT + (size_t)1*P_*D_     + (size_t)(h*E_)*D_;
  const uint16_t* WV = WT + (size_t)2*P_*D_     + (size_t)(h*E_)*D_;
  float4v zf = {0.f,0.f,0.f,0.f};

  // ---- K projection -> Kb[s][e]: pass eh yields e = q4*8+eh*4+r ----
  // byte addr = s*64 + slot*16 + eh*8, slot = q4 ^ (s&3)  (16B granule XOR)
  for (int eh=0; eh<2; eh++){
    float4v ka[2]; ka[0]=zf; ka[1]=zf;
    for (int kc=0; kc<4; kc++){
      short8 w = *(const short8*)(WK + (size_t)(eh*16 + c)*D_ + kc*32 + q4*8);
      for (int sj=0; sj<2; sj++) ka[sj] = MFMA32(w, af[sj][kc], ka[sj]);
    }
    float4v bk4 = *(const float4v*)(bk + h*E_ + q4*8 + eh*4);
    for (int sj=0; sj<2; sj++){
      int s = t0 + sj*16 + c;
      short4v kv = pack4(ka[sj] + bk4);
      *(short4v*)(Kb + s*32 + ((q4 ^ (s&3))<<3) + eh*4) = kv;
    }
  }
  // ---- V projection -> Vt[e][s] (scalar b16 transpose writes, identity e) ----
  for (int eh=0; eh<2; eh++){
    float4v va[2]; va[0]=zf; va[1]=zf;
    for (int kc=0; kc<4; kc++){
      short8 w = *(const short8*)(WV + (size_t)(eh*16 + c)*D_ + kc*32 + q4*8);
      for (int sj=0; sj<2; sj++) va[sj] = MFMA32(w, af[sj][kc], va[sj]);
    }
    float4v bv4 = *(const float4v*)(bv + h*E_ + eh*16 + q4*4);
    for (int sj=0; sj<2; sj++){
      int s = t0 + sj*16 + c;
      short4v vv = pack4(va[sj] + bv4);
      for (int r=0; r<4; r++){
        int e = eh*16 + q4*4 + r;
        Vt[e*T_ + ((((s>>2) + e) & 127)*4) + (s&3)] = (uint16_t)vv[r];
      }
    }
  }
  // ---- Q projection -> q8 regs: concat(pass0,pass1) = e chunk q4*8..q4*8+7 ----
  short8 q8[2];
  {
    short4v qtmp[2][2];
    for (int eh=0; eh<2; eh++){
      float4v qa[2]; qa[0]=zf; qa[1]=zf;
      for (int kc=0; kc<4; kc++){
        short8 w = *(const short8*)(WQ + (size_t)(eh*16 + c)*D_ + kc*32 + q4*8);
        for (int tj=0; tj<2; tj++) qa[tj] = MFMA32(w, af[tj][kc], qa[tj]);
      }
      float4v bq4 = *(const float4v*)(bq + h*E_ + q4*8 + eh*4);
      bq4 *= C2;
      for (int tj=0; tj<2; tj++) qtmp[tj][eh] = pack4(qa[tj] + bq4);
    }
    for (int tj=0; tj<2; tj++) q8[tj] = cat44(qtmp[tj][0], qtmp[tj][1]);
  }
  __syncthreads();

  // ---- s-loop: 32 s per iteration. S^T = K.Q^T (mask as C) -> exp2 -> PV ----
  float4v O[2][2], L4[2];
  for (int i=0;i<2;i++){ O[i][0]=zf; O[i][1]=zf; L4[i]=zf; }
  const short one_bf = (short)0x3F80;
  short8 ones8;
  for (int i=0;i<8;i++) ones8[i] = one_bf;

  for (int sb=0; sb<16; sb++){
    const int sq = sb*32;
    // mask (C operand) from LDS: 16-lane-group broadcast b128, conflict-free
    float4v mm0 = *(const float4v*)(Mrow + sq + q4*4);
    float4v mm1 = *(const float4v*)(Mrow + sq + 16 + q4*4);
    // K rows for both subtiles (one b128 each, conflict-free slot swizzle)
    const int srow0 = sq + c, srow1 = sq + 16 + c;
    short8 kb8_0 = *(const short8*)(Kb + srow0*32 + ((q4 ^ (srow0&3))<<3));
    short8 kb8_1 = *(const short8*)(Kb + srow1*32 + ((q4 ^ (srow1&3))<<3));
    // V quads in the SAME s-order as the P fragment's k-slots:
    //   k-slot q4*8+i  <->  s = sq + (i<4 ? q4*4+i : 16+q4*4+(i-4))
    const int u0 = sb*8 + q4, u1 = u0 + 4;
    short4v vA0 = *(const short4v*)(Vt + (size_t)c*T_      + ((u0 + c     ) & 127)*4);
    short4v vA1 = *(const short4v*)(Vt + (size_t)c*T_      + ((u1 + c     ) & 127)*4);
    short4v vB0 = *(const short4v*)(Vt + (size_t)(16+c)*T_ + ((u0 + 16 + c) & 127)*4);
    short4v vB1 = *(const short4v*)(Vt + (size_t)(16+c)*T_ + ((u1 + 16 + c) & 127)*4);
    short8 V8_0 = cat44(vA0, vA1);   // e 0..15
    short8 V8_1 = cat44(vB0, vB1);   // e 16..31
    for (int tj=0; tj<2; tj++){
      float4v st0 = MFMA32(kb8_0, q8[tj], mm0);
      float4v st1 = MFMA32(kb8_1, q8[tj], mm1);
      float4v p0, p1;
      p0[0] = EXP2F(st0[0]); p0[1] = EXP2F(st0[1]);
      p0[2] = EXP2F(st0[2]); p0[3] = EXP2F(st0[3]);
      p1[0] = EXP2F(st1[0]); p1[1] = EXP2F(st1[1]);
      p1[2] = EXP2F(st1[2]); p1[3] = EXP2F(st1[3]);
      short8 A8 = pack8(p0, p1);     // k-slots: [si0 quad | si1 quad]
      O[tj][0] = MFMA32(A8, V8_0, O[tj][0]);
      O[tj][1] = MFMA32(A8, V8_1, O[tj][1]);
      L4[tj]   = MFMA32(A8, ones8, L4[tj]);
    }
  }

  // ---- normalize + direct stores (lane = e, regs = t) ----
  for (int ti=0; ti<2; ti++){
    float4v linv;
    for (int r=0; r<4; r++) linv[r] = __builtin_amdgcn_rcpf(L4[ti][r]);
    for (int ej=0; ej<2; ej++){
      float4v v = O[ti][ej] * linv;
      for (int r=0; r<4; r++){
        int t = t0 + ti*16 + q4*4 + r;
        out[(size_t)((b*T_ + t)*M_ + m)*P_ + h*E_ + ej*16 + c] = v[r];
      }
    }
  }
}

extern "C" void kernel_launch(void* const* d_in, const int* in_sizes, int n_in,
                              void* d_out, int out_size, void* d_ws, size_t ws_size,
                              hipStream_t stream){
  const float* inp = (const float*)d_in[0];
  const int*   msk = (const int*)  d_in[1];
  const float* Wq  = (const float*)d_in[2];
  const float* bq  = (const float*)d_in[3];
  const float* Wk  = (const float*)d_in[4];
  const float* bk  = (const float*)d_in[5];
  const float* Wv  = (const float*)d_in[6];
  const float* bv  = (const float*)d_in[7];
  float* out = (float*)d_out;

  uint16_t* WT    = (uint16_t*)d_ws;                       // 196,608 B
  float*    maskf = (float*)((char*)d_ws + 196608);        // 262,144 B

  prep<<<dim3(640), dim3(256), 0, stream>>>(Wq, Wk, Wv, msk, WT, maskf);
  attn_fused<<<dim3(1024), dim3(1024), 0, stream>>>(inp, WT, bq, bk, bv, maskf, out);
}

// Round 4
// 180.918 us; speedup vs baseline: 2.3976x; 2.3976x over previous
//
#include <hip/hip_runtime.h>
#include <stdint.h>

#define B_ 8
#define T_ 512
#define M_ 16
#define D_ 128
#define P_ 256
#define H_ 8
#define E_ 32

typedef __attribute__((ext_vector_type(8))) short  short8;
typedef __attribute__((ext_vector_type(4))) short  short4v;
typedef __attribute__((ext_vector_type(4))) float  float4v;
typedef __attribute__((ext_vector_type(2))) unsigned int uint2v;
typedef __attribute__((ext_vector_type(4))) unsigned int uint4v;
typedef __attribute__((ext_vector_type(2))) __bf16 bf16x2;

#define MFMA32(a,b,c) __builtin_amdgcn_mfma_f32_16x16x32_bf16(a,b,c,0,0,0)   // K=32, short8 ops
#define EXP2F(x) __builtin_amdgcn_exp2f(x)

#define C2 0.2550332772062413f   // log2(e)/sqrt(E)

// cold-path scalar RNE (prep only)
static __device__ __forceinline__ unsigned short f2bf(float x){
  unsigned int u = __builtin_bit_cast(unsigned int, x);
  u += 0x7FFFu + ((u >> 16) & 1u);           // RNE
  return (unsigned short)(u >> 16);
}

// hot-path: plain __bf16 casts -> compiler emits v_cvt_pk_bf16_f32 (RNE).
static __device__ __forceinline__ unsigned int pk2(float a, float b){
  bf16x2 h; h[0] = (__bf16)a; h[1] = (__bf16)b;
  return __builtin_bit_cast(unsigned int, h);
}

static __device__ __forceinline__ short4v pack4(float4v v){
  uint2v u; u.x = pk2(v[0], v[1]); u.y = pk2(v[2], v[3]);
  return __builtin_bit_cast(short4v, u);
}

static __device__ __forceinline__ short8 pack8(float4v a, float4v b){
  uint4v u; u.x = pk2(a[0],a[1]); u.y = pk2(a[2],a[3]);
  u.z = pk2(b[0],b[1]); u.w = pk2(b[2],b[3]);
  return __builtin_bit_cast(short8, u);
}

static __device__ __forceinline__ short8 cat44(short4v lo, short4v hi){
  short8 r;
  r[0]=lo[0]; r[1]=lo[1]; r[2]=lo[2]; r[3]=lo[3];
  r[4]=hi[0]; r[5]=hi[1]; r[6]=hi[2]; r[7]=hi[3];
  return r;
}

// ------- kernel 0: WT[z][p][d] bf16 (Wq pre-scaled by C2) --------------------
// COALESCED (r4): p is the fastest thread index -> W[d*P + col] reads are
// contiguous per wave (the within-32 e-permutation stays inside the same
// cachelines). Writes (stride 128 els) are scattered but never stall.
// Q/K rows are PERMUTED so each projection pass directly produces the
// e-chunk-of-8 lane layout required by the K=32 MFMA operands:
//   storage row w = eh*16 + q4*4 + r  holds true column  e = q4*8 + eh*4 + r.
// Mask prep is gone: attn converts the raw int mask while staging to LDS.
__global__ void prep(const float* __restrict__ Wq, const float* __restrict__ Wk,
                     const float* __restrict__ Wv, uint16_t* __restrict__ WT){
  int idx = blockIdx.x*256 + threadIdx.x;      // 384*256 = 98304 = 3*P*D
  int p = idx & (P_-1);
  int d = (idx >> 8) & (D_-1);
  int z = idx >> 15;
  int col = p;
  if (z < 2){                                  // Q, K: permute within-head rows
    int w = p & 31;
    int e = ((w>>2)&3)*8 + ((w>>4)&1)*4 + (w&3);
    col = (p & ~31) | e;
  }
  const float* W = (z==0) ? Wq : (z==1) ? Wk : Wv;
  float sc = (z==0) ? C2 : 1.0f;
  WT[(z<<15) + (p<<7) + d] = f2bf(W[d*P_ + col] * sc);
}

// ---------------- fused QKV + masked attention, one block per (b,m,h) ------
// r4: round-2 structure restored (r3's forced 8 waves/EU capped VGPRs at 32
// against a ~95-reg live set -> scratch spills, 800MB WRITE_SIZE, 3.6x slower.
// Occupancy is hard-capped at 2 blocks x 8 waves by LDS; accept it, attack
// latency instead). Changes vs r2: mask row staged to LDS from the RAW int
// mask (global loads issued at kernel start, hidden under projections;
// removes 32 global loads from the s-loop -> broadcast LDS reads), and
// s_setprio(1) around the s-loop MFMA cluster (T5).
// All MFMAs are K=32 16x16x32 (rounds 1-2 operand-layout tricks):
//  - QK: one mfma per 16x16 S^T tile (weight-permute).
//  - PV+L: P fragment's natural per-lane s-order is a legal K=32 A-operand
//    with V supplied in the SAME s-order (cat44 of the two Vt quad reads).
__global__ __launch_bounds__(512, 4) void attn_fused(
    const float* __restrict__ inp, const uint16_t* __restrict__ WT,
    const float* __restrict__ bq, const float* __restrict__ bk,
    const float* __restrict__ bv, const int* __restrict__ mask,
    float* __restrict__ out){
  __shared__ __align__(16) uint16_t Kb[T_*E_];   // 32768 B  K[s][e] linear-e, slot-swizzled
  __shared__ __align__(16) uint16_t Vt[E_*T_];   // 32768 B  V^T[e][s], u-swizzled
  __shared__ __align__(16) float    Mrow[T_];    //  2048 B  additive mask row

  const int bx = blockIdx.x;                // 1024
  const int h = bx >> 7, bm = bx & 127;     // same-bm blocks -> same XCD (bx%8 = bm%8)
  const int b = bm >> 4, m = bm & 15;
  const int tid = threadIdx.x;
  const int wave = tid >> 6, lane = tid & 63;
  const int q4 = lane >> 4, c = lane & 15;
  const int t0 = wave*64;

  // stage mask row: raw int mask (stride-M dwords, L2/L3-hit, latency hidden
  // under the projection phase), converted to additive form in-register
  {
    int mv = mask[((size_t)(b*T_ + tid))*M_ + m];
    Mrow[tid] = mv ? 0.0f : -1e30f;
  }

  // ---- pack inp rows once: rows t0+tj*16+c, full d ----
  short8 af[4][4];   // [tj][kc]
  for (int tj=0; tj<4; tj++){
    const float* src = inp + (size_t)((b*T_ + t0 + tj*16 + c)*M_ + m)*D_;
    for (int kc=0; kc<4; kc++){
      float4v x0 = *(const float4v*)(src + kc*32 + q4*8);
      float4v x1 = *(const float4v*)(src + kc*32 + q4*8 + 4);
      af[tj][kc] = pack8(x0, x1);
    }
  }

  const uint16_t* WQ = WT                       + (size_t)(h*E_)*D_;
  const uint16_t* WK = WT + (size_t)1*P_*D_     + (size_t)(h*E_)*D_;
  const uint16_t* WV = WT + (size_t)2*P_*D_     + (size_t)(h*E_)*D_;
  float4v zf = {0.f,0.f,0.f,0.f};

  // ---- K projection -> Kb[s][e]: pass eh yields e = q4*8+eh*4+r ----
  // byte addr = s*64 + slot*16 + eh*8, slot = q4 ^ (s&3)  (16B granule XOR)
  for (int eh=0; eh<2; eh++){
    float4v ka[4]; for (int j=0;j<4;j++) ka[j]=zf;
    for (int kc=0; kc<4; kc++){
      short8 w = *(const short8*)(WK + (size_t)(eh*16 + c)*D_ + kc*32 + q4*8);
      for (int sj=0; sj<4; sj++) ka[sj] = MFMA32(w, af[sj][kc], ka[sj]);
    }
    float4v bk4 = *(const float4v*)(bk + h*E_ + q4*8 + eh*4);
    for (int sj=0; sj<4; sj++){
      int s = t0 + sj*16 + c;
      short4v kv = pack4(ka[sj] + bk4);
      *(short4v*)(Kb + s*32 + ((q4 ^ (s&3))<<3) + eh*4) = kv;
    }
  }
  // ---- V projection -> Vt[e][s] (scalar b16 transpose writes, identity e) ----
  for (int eh=0; eh<2; eh++){
    float4v va[4]; for (int j=0;j<4;j++) va[j]=zf;
    for (int kc=0; kc<4; kc++){
      short8 w = *(const short8*)(WV + (size_t)(eh*16 + c)*D_ + kc*32 + q4*8);
      for (int sj=0; sj<4; sj++) va[sj] = MFMA32(w, af[sj][kc], va[sj]);
    }
    float4v bv4 = *(const float4v*)(bv + h*E_ + eh*16 + q4*4);
    for (int sj=0; sj<4; sj++){
      int s = t0 + sj*16 + c;
      short4v vv = pack4(va[sj] + bv4);
      for (int r=0; r<4; r++){
        int e = eh*16 + q4*4 + r;
        Vt[e*T_ + ((((s>>2) + e) & 127)*4) + (s&3)] = (uint16_t)vv[r];
      }
    }
  }
  // ---- Q projection -> q8 regs: concat(pass0,pass1) = e chunk q4*8..q4*8+7 ----
  short8 q8[4];
  {
    short4v qtmp[4][2];
    for (int eh=0; eh<2; eh++){
      float4v qa[4]; for (int j=0;j<4;j++) qa[j]=zf;
      for (int kc=0; kc<4; kc++){
        short8 w = *(const short8*)(WQ + (size_t)(eh*16 + c)*D_ + kc*32 + q4*8);
        for (int tj=0; tj<4; tj++) qa[tj] = MFMA32(w, af[tj][kc], qa[tj]);
      }
      float4v bq4 = *(const float4v*)(bq + h*E_ + q4*8 + eh*4);
      bq4 *= C2;
      for (int tj=0; tj<4; tj++) qtmp[tj][eh] = pack4(qa[tj] + bq4);
    }
    for (int tj=0; tj<4; tj++) q8[tj] = cat44(qtmp[tj][0], qtmp[tj][1]);
  }
  __syncthreads();

  // ---- s-loop: 32 s per iteration. S^T = K.Q^T (mask as C) -> exp2 -> PV ----
  float4v O[4][2], L4[4];
  for (int i=0;i<4;i++){ O[i][0]=zf; O[i][1]=zf; L4[i]=zf; }
  const short one_bf = (short)0x3F80;
  short8 ones8;
  for (int i=0;i<8;i++) ones8[i] = one_bf;

  for (int sb=0; sb<16; sb++){
    const int sq = sb*32;
    // mask (C operand) from LDS: depends only on q4 -> 16-lane broadcast
    float4v mm0 = *(const float4v*)(Mrow + sq + q4*4);
    float4v mm1 = *(const float4v*)(Mrow + sq + 16 + q4*4);
    // K rows for both subtiles (one b128 each, conflict-free slot swizzle)
    const int srow0 = sq + c, srow1 = sq + 16 + c;
    short8 kb8_0 = *(const short8*)(Kb + srow0*32 + ((q4 ^ (srow0&3))<<3));
    short8 kb8_1 = *(const short8*)(Kb + srow1*32 + ((q4 ^ (srow1&3))<<3));
    // V quads in the SAME s-order as the P fragment's k-slots:
    //   k-slot q4*8+i  <->  s = sq + (i<4 ? q4*4+i : 16+q4*4+(i-4))
    const int u0 = sb*8 + q4, u1 = u0 + 4;
    short4v vA0 = *(const short4v*)(Vt + (size_t)c*T_      + ((u0 + c     ) & 127)*4);
    short4v vA1 = *(const short4v*)(Vt + (size_t)c*T_      + ((u1 + c     ) & 127)*4);
    short4v vB0 = *(const short4v*)(Vt + (size_t)(16+c)*T_ + ((u0 + 16 + c) & 127)*4);
    short4v vB1 = *(const short4v*)(Vt + (size_t)(16+c)*T_ + ((u1 + 16 + c) & 127)*4);
    short8 V8_0 = cat44(vA0, vA1);   // e 0..15
    short8 V8_1 = cat44(vB0, vB1);   // e 16..31
    __builtin_amdgcn_s_setprio(1);
    for (int tj=0; tj<4; tj++){
      float4v st0 = MFMA32(kb8_0, q8[tj], mm0);
      float4v st1 = MFMA32(kb8_1, q8[tj], mm1);
      float4v p0, p1;
      p0[0] = EXP2F(st0[0]); p0[1] = EXP2F(st0[1]);
      p0[2] = EXP2F(st0[2]); p0[3] = EXP2F(st0[3]);
      p1[0] = EXP2F(st1[0]); p1[1] = EXP2F(st1[1]);
      p1[2] = EXP2F(st1[2]); p1[3] = EXP2F(st1[3]);
      short8 A8 = pack8(p0, p1);     // k-slots: [si0 quad | si1 quad]
      O[tj][0] = MFMA32(A8, V8_0, O[tj][0]);
      O[tj][1] = MFMA32(A8, V8_1, O[tj][1]);
      L4[tj]   = MFMA32(A8, ones8, L4[tj]);
    }
    __builtin_amdgcn_s_setprio(0);
  }

  // ---- normalize + direct stores (lane = e, regs = t) ----
  for (int ti=0; ti<4; ti++){
    float4v linv;
    for (int r=0; r<4; r++) linv[r] = __builtin_amdgcn_rcpf(L4[ti][r]);
    for (int ej=0; ej<2; ej++){
      float4v v = O[ti][ej] * linv;
      for (int r=0; r<4; r++){
        int t = t0 + ti*16 + q4*4 + r;
        out[(size_t)((b*T_ + t)*M_ + m)*P_ + h*E_ + ej*16 + c] = v[r];
      }
    }
  }
}

extern "C" void kernel_launch(void* const* d_in, const int* in_sizes, int n_in,
                              void* d_out, int out_size, void* d_ws, size_t ws_size,
                              hipStream_t stream){
  const float* inp = (const float*)d_in[0];
  const int*   msk = (const int*)  d_in[1];
  const float* Wq  = (const float*)d_in[2];
  const float* bq  = (const float*)d_in[3];
  const float* Wk  = (const float*)d_in[4];
  const float* bk  = (const float*)d_in[5];
  const float* Wv  = (const float*)d_in[6];
  const float* bv  = (const float*)d_in[7];
  float* out = (float*)d_out;

  uint16_t* WT = (uint16_t*)d_ws;                          // 196,608 B

  prep<<<dim3(384), dim3(256), 0, stream>>>(Wq, Wk, Wv, WT);
  attn_fused<<<dim3(1024), dim3(512), 0, stream>>>(inp, WT, bq, bk, bv, msk, out);
}

// Round 5
// 166.989 us; speedup vs baseline: 2.5976x; 1.0834x over previous
//
#include <hip/hip_runtime.h>
#include <stdint.h>

#define B_ 8
#define T_ 512
#define M_ 16
#define D_ 128
#define P_ 256
#define H_ 8
#define E_ 32

typedef __attribute__((ext_vector_type(8))) short  short8;
typedef __attribute__((ext_vector_type(4))) short  short4v;
typedef __attribute__((ext_vector_type(4))) float  float4v;
typedef __attribute__((ext_vector_type(2))) unsigned int uint2v;
typedef __attribute__((ext_vector_type(4))) unsigned int uint4v;
typedef __attribute__((ext_vector_type(2))) __bf16 bf16x2;

#define MFMA32(a,b,c) __builtin_amdgcn_mfma_f32_16x16x32_bf16(a,b,c,0,0,0)   // K=32, short8 ops
#define EXP2F(x) __builtin_amdgcn_exp2f(x)

#define C2 0.2550332772062413f   // log2(e)/sqrt(E)

// cold-path scalar RNE (prep only)
static __device__ __forceinline__ unsigned short f2bf(float x){
  unsigned int u = __builtin_bit_cast(unsigned int, x);
  u += 0x7FFFu + ((u >> 16) & 1u);           // RNE
  return (unsigned short)(u >> 16);
}

// hot-path: plain __bf16 casts -> compiler emits v_cvt_pk_bf16_f32 (RNE).
static __device__ __forceinline__ unsigned int pk2(float a, float b){
  bf16x2 h; h[0] = (__bf16)a; h[1] = (__bf16)b;
  return __builtin_bit_cast(unsigned int, h);
}

static __device__ __forceinline__ short4v pack4(float4v v){
  uint2v u; u.x = pk2(v[0], v[1]); u.y = pk2(v[2], v[3]);
  return __builtin_bit_cast(short4v, u);
}

static __device__ __forceinline__ short8 pack8(float4v a, float4v b){
  uint4v u; u.x = pk2(a[0],a[1]); u.y = pk2(a[2],a[3]);
  u.z = pk2(b[0],b[1]); u.w = pk2(b[2],b[3]);
  return __builtin_bit_cast(short8, u);
}

static __device__ __forceinline__ short8 cat44(short4v lo, short4v hi){
  short8 r;
  r[0]=lo[0]; r[1]=lo[1]; r[2]=lo[2]; r[3]=lo[3];
  r[4]=hi[0]; r[5]=hi[1]; r[6]=hi[2]; r[7]=hi[3];
  return r;
}

// ------- kernel 0: WT[z][p][d] bf16 (Wq pre-scaled by C2) --------------------
// Coalesced: p fastest -> contiguous reads. Q/K rows permuted so projection
// passes directly produce the e-chunk-of-8 layout for K=32 MFMA operands:
//   storage row w = eh*16 + q4*4 + r  holds true column  e = q4*8 + eh*4 + r.
__global__ void prep(const float* __restrict__ Wq, const float* __restrict__ Wk,
                     const float* __restrict__ Wv, uint16_t* __restrict__ WT){
  int idx = blockIdx.x*256 + threadIdx.x;      // 384*256 = 98304 = 3*P*D
  int p = idx & (P_-1);
  int d = (idx >> 8) & (D_-1);
  int z = idx >> 15;
  int col = p;
  if (z < 2){                                  // Q, K: permute within-head rows
    int w = p & 31;
    int e = ((w>>2)&3)*8 + ((w>>4)&1)*4 + (w&3);
    col = (p & ~31) | e;
  }
  const float* W = (z==0) ? Wq : (z==1) ? Wk : Wv;
  float sc = (z==0) ? C2 : 1.0f;
  WT[(z<<15) + (p<<7) + d] = f2bf(W[d*P_ + col] * sc);
}

// ---------------- fused QKV + masked attention, one block per (b,m,h) ------
// r5: attn pinned at 102us across 3 rounds of pipe-work cuts -> latency-bound
// on the af GATHER (32 loads x 16 scattered cachelines, pack-pair dependent,
// ~60 free VGPRs -> ~2-deep MLP -> 10-15k stall cyc/wave). Fix: wave-private
// COALESCED staging of inp through the (union'd) LDS scratch as bf16:
//   - loads: 4 rows x 256B contiguous per instr, 8 independent in flight
//   - bf16 conversion BEFORE LDS (kills the 16 pack8 too)
//   - fragments come back as single swizzled ds_read_b128
// Wave-private rows -> no staging barriers; one syncthreads before the
// projections overwrite the scratch with Kb/Vt. Bit-identical output.
__global__ __launch_bounds__(512, 4) void attn_fused(
    const float* __restrict__ inp, const uint16_t* __restrict__ WT,
    const float* __restrict__ bq, const float* __restrict__ bk,
    const float* __restrict__ bv, const int* __restrict__ mask,
    float* __restrict__ out){
  // union: bytes [0,65536) = staging scratch (512 rows x 128B bf16), later
  // Kb = [0,32768) K[s][e] slot-swizzled, Vt = [32768,65536) V^T[e][s];
  // bytes [65536,67584) = Mrow (additive mask, f32)
  __shared__ __align__(16) uint16_t smem[(65536 + 2048)/2];
  uint16_t* Kb   = smem;              // uint16 units: rows of 32 (64B)
  uint16_t* Vt   = smem + 16384;
  float*    Mrow = (float*)(smem + 32768);

  const int bx = blockIdx.x;                // 1024
  const int h = bx >> 7, bm = bx & 127;     // same-bm blocks -> same XCD (bx%8 = bm%8)
  const int b = bm >> 4, m = bm & 15;
  const int tid = threadIdx.x;
  const int wave = tid >> 6, lane = tid & 63;
  const int q4 = lane >> 4, c = lane & 15;
  const int t0 = wave*64;

  // stage mask row: raw int mask (L2/L3-hit, hidden under staging/projections)
  {
    int mv = mask[((size_t)(b*T_ + tid))*M_ + m];
    Mrow[tid] = mv ? 0.0f : -1e30f;
  }

  // ---- stage inp -> LDS (bf16, swizzled) -> read MFMA fragments ----
  // scratch row t: 128B = current 64-d half, 16B slots, slot ^= (t&7)
  short8 af[4][4];   // [tj][kc]
  {
    const float* src0 = inp + (size_t)((b*T_ + t0)*M_ + m)*D_ + c*4;
    for (int hh=0; hh<2; hh++){              // d halves: [0,64), [64,128)
      for (int jb=0; jb<2; jb++){            // 2 batches of 8 loads (reg cap)
        float4v stg[8];
        for (int j=0; j<8; j++){
          int r = jb*32 + j*4 + q4;          // row within wave's 64
          stg[j] = *(const float4v*)(src0 + (size_t)r*(M_*D_) + hh*64);
        }
        for (int j=0; j<8; j++){
          int r = t0 + jb*32 + j*4 + q4;
          short4v s4 = pack4(stg[j]);
          *(short4v*)(smem + r*64 + ((((c>>1) ^ (r&7))<<3) + ((c&1)<<2))) = s4;
        }
      }
      // fragments of this half: kc = hh*2+kh, d = kc*32 + q4*8 .. +7
      for (int tj=0; tj<4; tj++){
        int r2 = t0 + tj*16 + c;
        af[tj][hh*2+0] = *(const short8*)(smem + r2*64 + (((q4    ) ^ (r2&7))<<3));
        af[tj][hh*2+1] = *(const short8*)(smem + r2*64 + (((q4 | 4) ^ (r2&7))<<3));
      }
      // half1 staging overwrites same rows: same-wave DS ops execute in order
    }
  }
  __syncthreads();   // all waves done with scratch before Kb/Vt writes

  const uint16_t* WQ = WT                       + (size_t)(h*E_)*D_;
  const uint16_t* WK = WT + (size_t)1*P_*D_     + (size_t)(h*E_)*D_;
  const uint16_t* WV = WT + (size_t)2*P_*D_     + (size_t)(h*E_)*D_;
  float4v zf = {0.f,0.f,0.f,0.f};

  // ---- K projection -> Kb[s][e]: pass eh yields e = q4*8+eh*4+r ----
  // byte addr = s*64 + slot*16 + eh*8, slot = q4 ^ (s&3)  (16B granule XOR)
  for (int eh=0; eh<2; eh++){
    float4v ka[4]; for (int j=0;j<4;j++) ka[j]=zf;
    for (int kc=0; kc<4; kc++){
      short8 w = *(const short8*)(WK + (size_t)(eh*16 + c)*D_ + kc*32 + q4*8);
      for (int sj=0; sj<4; sj++) ka[sj] = MFMA32(w, af[sj][kc], ka[sj]);
    }
    float4v bk4 = *(const float4v*)(bk + h*E_ + q4*8 + eh*4);
    for (int sj=0; sj<4; sj++){
      int s = t0 + sj*16 + c;
      short4v kv = pack4(ka[sj] + bk4);
      *(short4v*)(Kb + s*32 + ((q4 ^ (s&3))<<3) + eh*4) = kv;
    }
  }
  // ---- V projection -> Vt[e][s] (scalar b16 transpose writes, identity e) ----
  for (int eh=0; eh<2; eh++){
    float4v va[4]; for (int j=0;j<4;j++) va[j]=zf;
    for (int kc=0; kc<4; kc++){
      short8 w = *(const short8*)(WV + (size_t)(eh*16 + c)*D_ + kc*32 + q4*8);
      for (int sj=0; sj<4; sj++) va[sj] = MFMA32(w, af[sj][kc], va[sj]);
    }
    float4v bv4 = *(const float4v*)(bv + h*E_ + eh*16 + q4*4);
    for (int sj=0; sj<4; sj++){
      int s = t0 + sj*16 + c;
      short4v vv = pack4(va[sj] + bv4);
      for (int r=0; r<4; r++){
        int e = eh*16 + q4*4 + r;
        Vt[e*T_ + ((((s>>2) + e) & 127)*4) + (s&3)] = (uint16_t)vv[r];
      }
    }
  }
  // ---- Q projection -> q8 regs: concat(pass0,pass1) = e chunk q4*8..q4*8+7 ----
  short8 q8[4];
  {
    short4v qtmp[4][2];
    for (int eh=0; eh<2; eh++){
      float4v qa[4]; for (int j=0;j<4;j++) qa[j]=zf;
      for (int kc=0; kc<4; kc++){
        short8 w = *(const short8*)(WQ + (size_t)(eh*16 + c)*D_ + kc*32 + q4*8);
        for (int tj=0; tj<4; tj++) qa[tj] = MFMA32(w, af[tj][kc], qa[tj]);
      }
      float4v bq4 = *(const float4v*)(bq + h*E_ + q4*8 + eh*4);
      bq4 *= C2;
      for (int tj=0; tj<4; tj++) qtmp[tj][eh] = pack4(qa[tj] + bq4);
    }
    for (int tj=0; tj<4; tj++) q8[tj] = cat44(qtmp[tj][0], qtmp[tj][1]);
  }
  __syncthreads();

  // ---- s-loop: 32 s per iteration. S^T = K.Q^T (mask as C) -> exp2 -> PV ----
  float4v O[4][2], L4[4];
  for (int i=0;i<4;i++){ O[i][0]=zf; O[i][1]=zf; L4[i]=zf; }
  const short one_bf = (short)0x3F80;
  short8 ones8;
  for (int i=0;i<8;i++) ones8[i] = one_bf;

  for (int sb=0; sb<16; sb++){
    const int sq = sb*32;
    // mask (C operand) from LDS: depends only on q4 -> 16-lane broadcast
    float4v mm0 = *(const float4v*)(Mrow + sq + q4*4);
    float4v mm1 = *(const float4v*)(Mrow + sq + 16 + q4*4);
    // K rows for both subtiles (one b128 each, slot swizzle)
    const int srow0 = sq + c, srow1 = sq + 16 + c;
    short8 kb8_0 = *(const short8*)(Kb + srow0*32 + ((q4 ^ (srow0&3))<<3));
    short8 kb8_1 = *(const short8*)(Kb + srow1*32 + ((q4 ^ (srow1&3))<<3));
    // V quads in the SAME s-order as the P fragment's k-slots:
    //   k-slot q4*8+i  <->  s = sq + (i<4 ? q4*4+i : 16+q4*4+(i-4))
    const int u0 = sb*8 + q4, u1 = u0 + 4;
    short4v vA0 = *(const short4v*)(Vt + (size_t)c*T_      + ((u0 + c     ) & 127)*4);
    short4v vA1 = *(const short4v*)(Vt + (size_t)c*T_      + ((u1 + c     ) & 127)*4);
    short4v vB0 = *(const short4v*)(Vt + (size_t)(16+c)*T_ + ((u0 + 16 + c) & 127)*4);
    short4v vB1 = *(const short4v*)(Vt + (size_t)(16+c)*T_ + ((u1 + 16 + c) & 127)*4);
    short8 V8_0 = cat44(vA0, vA1);   // e 0..15
    short8 V8_1 = cat44(vB0, vB1);   // e 16..31
    __builtin_amdgcn_s_setprio(1);
    for (int tj=0; tj<4; tj++){
      float4v st0 = MFMA32(kb8_0, q8[tj], mm0);
      float4v st1 = MFMA32(kb8_1, q8[tj], mm1);
      float4v p0, p1;
      p0[0] = EXP2F(st0[0]); p0[1] = EXP2F(st0[1]);
      p0[2] = EXP2F(st0[2]); p0[3] = EXP2F(st0[3]);
      p1[0] = EXP2F(st1[0]); p1[1] = EXP2F(st1[1]);
      p1[2] = EXP2F(st1[2]); p1[3] = EXP2F(st1[3]);
      short8 A8 = pack8(p0, p1);     // k-slots: [si0 quad | si1 quad]
      O[tj][0] = MFMA32(A8, V8_0, O[tj][0]);
      O[tj][1] = MFMA32(A8, V8_1, O[tj][1]);
      L4[tj]   = MFMA32(A8, ones8, L4[tj]);
    }
    __builtin_amdgcn_s_setprio(0);
  }

  // ---- normalize + direct stores (lane = e, regs = t) ----
  for (int ti=0; ti<4; ti++){
    float4v linv;
    for (int r=0; r<4; r++) linv[r] = __builtin_amdgcn_rcpf(L4[ti][r]);
    for (int ej=0; ej<2; ej++){
      float4v v = O[ti][ej] * linv;
      for (int r=0; r<4; r++){
        int t = t0 + ti*16 + q4*4 + r;
        out[(size_t)((b*T_ + t)*M_ + m)*P_ + h*E_ + ej*16 + c] = v[r];
      }
    }
  }
}

extern "C" void kernel_launch(void* const* d_in, const int* in_sizes, int n_in,
                              void* d_out, int out_size, void* d_ws, size_t ws_size,
                              hipStream_t stream){
  const float* inp = (const float*)d_in[0];
  const int*   msk = (const int*)  d_in[1];
  const float* Wq  = (const float*)d_in[2];
  const float* bq  = (const float*)d_in[3];
  const float* Wk  = (const float*)d_in[4];
  const float* bk  = (const float*)d_in[5];
  const float* Wv  = (const float*)d_in[6];
  const float* bv  = (const float*)d_in[7];
  float* out = (float*)d_out;

  uint16_t* WT = (uint16_t*)d_ws;                          // 196,608 B

  prep<<<dim3(384), dim3(256), 0, stream>>>(Wq, Wk, Wv, WT);
  attn_fused<<<dim3(1024), dim3(512), 0, stream>>>(inp, WT, bq, bk, bv, msk, out);
}